// Round 3
// baseline (570.238 us; speedup 1.0000x reference)
//
#include <hip/hip_runtime.h>

// ---------------------------------------------------------------------------
// GCN model, re-associated: per layer h = relu((A_hat @ h_prev) @ W^T + b);
// pool BEFORE gcn_out linear. All fp32.
// k_agg: wave-per-node, register-staged neighbor tiles, unconditional clamped
// gathers (8-deep MLP per thread). csr_w precomputed at scatter time.
// ---------------------------------------------------------------------------

__global__ void k_zero(int* deg, float* pool, float* cnt, int* csr_pad,
                       int N, int G) {
    int i = blockIdx.x * blockDim.x + threadIdx.x;
    if (i < N) deg[i] = 0;
    if (i < G * 128) pool[i] = 0.f;
    if (i < G) cnt[i] = 0.f;
    if (i < 16) csr_pad[i] = 0;          // pad region of csr_src
}

__global__ void k_degree(const int* __restrict__ col, int* __restrict__ deg, int E) {
    int e = blockIdx.x * blockDim.x + threadIdx.x;
    if (e < E) atomicAdd(&deg[col[e]], 1);
}

// ---- 3-phase multi-block exclusive scan of deg -> rowptr/cursor (+dinv) ----
__global__ __launch_bounds__(256) void k_scan1(const int* __restrict__ deg,
                                               int* __restrict__ bsum, int N) {
    int t = threadIdx.x;
    int i = blockIdx.x * 256 + t;
    int v = (i < N) ? deg[i] : 0;
    #pragma unroll
    for (int off = 32; off > 0; off >>= 1) v += __shfl_xor(v, off, 64);
    __shared__ int ws[4];
    if ((t & 63) == 0) ws[t >> 6] = v;
    __syncthreads();
    if (t == 0) bsum[blockIdx.x] = ws[0] + ws[1] + ws[2] + ws[3];
}

__global__ __launch_bounds__(256) void k_scan2(int* __restrict__ bsum, int NB) {
    int t = threadIdx.x, lane = t & 63, wv = t >> 6;
    int v = (t < NB) ? bsum[t] : 0;
    int x = v;
    #pragma unroll
    for (int off = 1; off < 64; off <<= 1) {
        int u = __shfl_up(x, off, 64);
        if (lane >= off) x += u;
    }
    __shared__ int ws[4];
    if (lane == 63) ws[wv] = x;
    __syncthreads();
    int woff = 0;
    for (int w = 0; w < wv; ++w) woff += ws[w];
    if (t < NB) bsum[t] = woff + x - v;
}

__global__ __launch_bounds__(256) void k_scan3(const int* __restrict__ deg,
                                               const int* __restrict__ bsum,
                                               int* __restrict__ rowptr,
                                               int* __restrict__ cursor,
                                               float* __restrict__ dinv,
                                               int N, int E) {
    int t = threadIdx.x, lane = t & 63, wv = t >> 6;
    int i = blockIdx.x * 256 + t;
    int v = (i < N) ? deg[i] : 0;
    int x = v;
    #pragma unroll
    for (int off = 1; off < 64; off <<= 1) {
        int u = __shfl_up(x, off, 64);
        if (lane >= off) x += u;
    }
    __shared__ int ws[4];
    if (lane == 63) ws[wv] = x;
    __syncthreads();
    int woff = 0;
    for (int w = 0; w < wv; ++w) woff += ws[w];
    int excl = bsum[blockIdx.x] + woff + (x - v);
    if (i < N) {
        rowptr[i] = excl;
        cursor[i] = excl;
        dinv[i] = rsqrtf((float)v + 1.0f);
    }
    if (i == 0) rowptr[N] = E;
}

// Also stores csr_w[pos] = dinv[src] so the per-layer hot loop has no gather.
__global__ void k_scatter(const int* __restrict__ row, const int* __restrict__ col,
                          const float* __restrict__ dinv,
                          int* __restrict__ cursor, int* __restrict__ csr_src,
                          float* __restrict__ csr_w, int E) {
    int e = blockIdx.x * blockDim.x + threadIdx.x;
    if (e < E) {
        int pos = atomicAdd(&cursor[col[e]], 1);
        int r = row[e];
        csr_src[pos] = r;
        csr_w[pos] = dinv[r];
    }
}

// WT[l][k][o] = gcn_W[l][o][k], l in {0,1,2}
__global__ void k_transpose_w(const float* __restrict__ gcnW, float* __restrict__ WT) {
    int idx = blockIdx.x * 256 + threadIdx.x;   // 49152 threads
    int l = idx >> 14, rem = idx & 16383;
    int k = rem >> 7, o = rem & 127;
    WT[idx] = gcnW[l * 16384 + o * 128 + k];
}

// y[n] = dinv[n] * sum_{src} csr_w*h[src] + dinv[n]^2 * h[n]
// One wave per node; 4 nodes per 256-thread block. lane&31 = feature group
// (float4), lane>>5 = neighbor slot. Neighbor tiles of 16 staged in registers
// (lanes 0..15 of each 16-segment), broadcast via __shfl width 16.
// All gather loads are UNCONDITIONAL (csr_src padded) -> 8-deep MLP.
__global__ __launch_bounds__(256) void k_agg(const float* __restrict__ h,
                                             float* __restrict__ y,
                                             const float* __restrict__ dinv,
                                             const int* __restrict__ rowptr,
                                             const int* __restrict__ csr_src,
                                             const float* __restrict__ csr_w,
                                             int N) {
    const int lane = threadIdx.x & 63;
    const int n = blockIdx.x * 4 + (threadIdx.x >> 6);
    if (n >= N) return;
    const int fg = lane & 31;
    const int slot = lane >> 5;
    const int s = rowptr[n], e = rowptr[n + 1];

    float4 acc = make_float4(0.f, 0.f, 0.f, 0.f);
    for (int base = s; base < e; base += 16) {
        int li = base + (lane & 15);
        int src_l = csr_src[li];                   // padded: always in-bounds
        float w_l = (li < e) ? csr_w[li] : 0.f;    // mask by weight, not branch
        #pragma unroll
        for (int i = 0; i < 8; ++i) {
            int j = 2 * i + slot;
            int src = __shfl(src_l, j, 16);
            float w = __shfl(w_l, j, 16);
            const float4 v = *(const float4*)(h + (size_t)src * 128 + fg * 4);
            acc.x += w * v.x; acc.y += w * v.y;
            acc.z += w * v.z; acc.w += w * v.w;
        }
    }
    // combine the two neighbor slots (lanes i and i+32 hold partial sums)
    acc.x += __shfl_xor(acc.x, 32, 64);
    acc.y += __shfl_xor(acc.y, 32, 64);
    acc.z += __shfl_xor(acc.z, 32, 64);
    acc.w += __shfl_xor(acc.w, 32, 64);
    if (slot == 0) {
        float dn = dinv[n], dn2 = dn * dn;
        float4 hv = *(const float4*)(h + (size_t)n * 128 + fg * 4);
        float4 o;
        o.x = acc.x * dn + dn2 * hv.x;
        o.y = acc.y * dn + dn2 * hv.y;
        o.z = acc.z * dn + dn2 * hv.z;
        o.w = acc.w * dn + dn2 * hv.w;
        *(float4*)(y + (size_t)n * 128 + fg * 4) = o;
    }
}

// C[N,128] = relu(A[N,128] @ W^T + bias). WT is [k][o].
// A tile stored TRANSPOSED in LDS (As[k][r], stride 68): per-k row fragment is
// one ds_read_b128 (2-way banks = free) instead of 4 conflicted ds_read_b32.
__global__ __launch_bounds__(256, 2) void k_matmul(const float* __restrict__ A,
                                                   const float* __restrict__ WT,
                                                   const float* __restrict__ bias,
                                                   float* __restrict__ C, int N) {
    __shared__ float As[128 * 68];   // 34816 B, As[k*68 + r]
    __shared__ float Ws[64 * 128];   // 32768 B, per-kt tile [kk][o]
    const int tid = threadIdx.x;
    const int row0 = blockIdx.x * 64;
    const int tr = tid >> 4;     // 0..15 -> rows 4*tr..+3
    const int tc = tid & 15;     // 0..15 -> cols 8*tc..+7

    // stage A tile transposed: coalesced float4 global read, 4 scalar LDS writes
    #pragma unroll
    for (int i = 0; i < 8; ++i) {
        int v = tid + i * 256;             // 0..2047 float4 slots
        int r = v >> 5, k4 = v & 31;
        int gr = row0 + r;
        float4 val = make_float4(0.f, 0.f, 0.f, 0.f);
        if (gr < N) val = *(const float4*)(A + (size_t)gr * 128 + k4 * 4);
        int kb = k4 * 4;
        As[(kb + 0) * 68 + r] = val.x;
        As[(kb + 1) * 68 + r] = val.y;
        As[(kb + 2) * 68 + r] = val.z;
        As[(kb + 3) * 68 + r] = val.w;
    }

    float acc[4][8];
    #pragma unroll
    for (int j = 0; j < 4; ++j)
        #pragma unroll
        for (int c = 0; c < 8; ++c) acc[j][c] = 0.f;

    for (int kt = 0; kt < 2; ++kt) {
        __syncthreads();
        #pragma unroll
        for (int i = 0; i < 8; ++i) {
            int v = tid + i * 256;
            int kk = v >> 5, o4 = v & 31;
            *(float4*)(&Ws[kk * 128 + o4 * 4]) =
                *(const float4*)(WT + (size_t)(kt * 64 + kk) * 128 + o4 * 4);
        }
        __syncthreads();
        #pragma unroll
        for (int kc = 0; kc < 16; ++kc) {
            const int kk = kc * 4;
            float4 a4[4];   // a4[i] = rows 4tr..4tr+3 at k = kt*64+kk+i
            #pragma unroll
            for (int i = 0; i < 4; ++i)
                a4[i] = *(const float4*)&As[(size_t)(kt * 64 + kk + i) * 68 + 4 * tr];
            #pragma unroll
            for (int i = 0; i < 4; ++i) {
                float4 w0 = *(const float4*)(&Ws[(kk + i) * 128 + tc * 8]);
                float4 w1 = *(const float4*)(&Ws[(kk + i) * 128 + tc * 8 + 4]);
                float aj[4] = {a4[i].x, a4[i].y, a4[i].z, a4[i].w};
                #pragma unroll
                for (int j = 0; j < 4; ++j) {
                    acc[j][0] += aj[j] * w0.x; acc[j][1] += aj[j] * w0.y;
                    acc[j][2] += aj[j] * w0.z; acc[j][3] += aj[j] * w0.w;
                    acc[j][4] += aj[j] * w1.x; acc[j][5] += aj[j] * w1.y;
                    acc[j][6] += aj[j] * w1.z; acc[j][7] += aj[j] * w1.w;
                }
            }
        }
    }

    float4 b0 = *(const float4*)(bias + tc * 8);
    float4 b1 = *(const float4*)(bias + tc * 8 + 4);
    #pragma unroll
    for (int j = 0; j < 4; ++j) {
        int gr = row0 + 4 * tr + j;
        if (gr < N) {
            float4 o0 = make_float4(fmaxf(acc[j][0] + b0.x, 0.f),
                                    fmaxf(acc[j][1] + b0.y, 0.f),
                                    fmaxf(acc[j][2] + b0.z, 0.f),
                                    fmaxf(acc[j][3] + b0.w, 0.f));
            float4 o1 = make_float4(fmaxf(acc[j][4] + b1.x, 0.f),
                                    fmaxf(acc[j][5] + b1.y, 0.f),
                                    fmaxf(acc[j][6] + b1.z, 0.f),
                                    fmaxf(acc[j][7] + b1.w, 0.f));
            *(float4*)(C + (size_t)gr * 128 + tc * 8) = o0;
            *(float4*)(C + (size_t)gr * 128 + tc * 8 + 4) = o1;
        }
    }
}

// Mean-pool accumulate (batch sorted). 8 subgroups of 32 lanes per block.
__global__ __launch_bounds__(256) void k_pool(const float* __restrict__ h,
                                              const int* __restrict__ batch,
                                              float* __restrict__ pool,
                                              float* __restrict__ cnt, int N) {
    int t = threadIdx.x;
    int fg = t & 31, sg = t >> 5;
    int n0 = blockIdx.x * 256 + sg * 32;
    if (n0 >= N) return;
    int n1 = min(n0 + 32, N);
    int gprev = batch[n0];
    float4 racc = make_float4(0.f, 0.f, 0.f, 0.f);
    float rcnt = 0.f;
    for (int n = n0; n < n1; ++n) {
        int g = batch[n];
        if (g != gprev) {
            float* dst = pool + (size_t)gprev * 128 + fg * 4;
            atomicAdd(dst + 0, racc.x); atomicAdd(dst + 1, racc.y);
            atomicAdd(dst + 2, racc.z); atomicAdd(dst + 3, racc.w);
            if (fg == 0) atomicAdd(&cnt[gprev], rcnt);
            racc = make_float4(0.f, 0.f, 0.f, 0.f); rcnt = 0.f; gprev = g;
        }
        float4 v = *(const float4*)(h + (size_t)n * 128 + fg * 4);
        racc.x += v.x; racc.y += v.y; racc.z += v.z; racc.w += v.w;
        rcnt += 1.f;
    }
    float* dst = pool + (size_t)gprev * 128 + fg * 4;
    atomicAdd(dst + 0, racc.x); atomicAdd(dst + 1, racc.y);
    atomicAdd(dst + 2, racc.z); atomicAdd(dst + 3, racc.w);
    if (fg == 0) atomicAdd(&cnt[gprev], rcnt);
}

// Fused head. gcn branch: mean -> gcn_out linear (moved after pooling).
__global__ __launch_bounds__(256) void k_head(
    const float* __restrict__ pool, const float* __restrict__ cnt,
    const float* __restrict__ gcnoW, const float* __restrict__ gcnob,
    const float* __restrict__ mol,
    const float* __restrict__ mlpW, const float* __restrict__ mlpb,
    const float* __restrict__ mloW, const float* __restrict__ mlob,
    const float* __restrict__ pW1, const float* __restrict__ pb1,
    const float* __restrict__ pW2, const float* __restrict__ pb2,
    const float* __restrict__ oW, const float* __restrict__ ob,
    float* __restrict__ out) {
    int g = blockIdx.x, t = threadIdx.x;
    __shared__ float s0[256], s1[256], s2[192], mean[128], red[256];

    s0[t] = mol[(size_t)g * 256 + t];
    if (t < 128) {
        float c = cnt[g];
        mean[t] = pool[(size_t)g * 128 + t] / fmaxf(c, 1.f);
    }
    __syncthreads();

    float acc = mlpb[t];
    {
        const float4* w = (const float4*)(mlpW + (size_t)t * 256);
        #pragma unroll 4
        for (int k4 = 0; k4 < 64; ++k4) {
            float4 wv = w[k4];
            acc += s0[k4*4+0]*wv.x + s0[k4*4+1]*wv.y + s0[k4*4+2]*wv.z + s0[k4*4+3]*wv.w;
        }
    }
    s1[t] = fmaxf(acc, 0.f);
    __syncthreads();

    acc = mlpb[256 + t];
    {
        const float4* w = (const float4*)(mlpW + 65536 + (size_t)t * 256);
        #pragma unroll 4
        for (int k4 = 0; k4 < 64; ++k4) {
            float4 wv = w[k4];
            acc += s1[k4*4+0]*wv.x + s1[k4*4+1]*wv.y + s1[k4*4+2]*wv.z + s1[k4*4+3]*wv.w;
        }
    }
    s0[t] = fmaxf(acc, 0.f);
    __syncthreads();

    if (t < 64) {
        float a2 = mlob[t];
        const float4* w = (const float4*)(mloW + (size_t)t * 256);
        #pragma unroll 4
        for (int k4 = 0; k4 < 64; ++k4) {
            float4 wv = w[k4];
            a2 += s0[k4*4+0]*wv.x + s0[k4*4+1]*wv.y + s0[k4*4+2]*wv.z + s0[k4*4+3]*wv.w;
        }
        s2[128 + t] = fmaxf(a2, 0.f);
    } else if (t < 192) {
        int o = t - 64;
        float a2 = gcnob[o];
        const float4* w = (const float4*)(gcnoW + (size_t)o * 128);
        #pragma unroll 4
        for (int k4 = 0; k4 < 32; ++k4) {
            float4 wv = w[k4];
            a2 += mean[k4*4+0]*wv.x + mean[k4*4+1]*wv.y + mean[k4*4+2]*wv.z + mean[k4*4+3]*wv.w;
        }
        s2[o] = a2;   // no relu on gcn_out
    }
    __syncthreads();

    acc = pb1[t];
    {
        const float4* w = (const float4*)(pW1 + (size_t)t * 192);
        #pragma unroll 4
        for (int k4 = 0; k4 < 48; ++k4) {
            float4 wv = w[k4];
            acc += s2[k4*4+0]*wv.x + s2[k4*4+1]*wv.y + s2[k4*4+2]*wv.z + s2[k4*4+3]*wv.w;
        }
    }
    s1[t] = fmaxf(acc, 0.f);
    __syncthreads();

    acc = pb2[t];
    {
        const float4* w = (const float4*)(pW2 + (size_t)t * 256);
        #pragma unroll 4
        for (int k4 = 0; k4 < 64; ++k4) {
            float4 wv = w[k4];
            acc += s1[k4*4+0]*wv.x + s1[k4*4+1]*wv.y + s1[k4*4+2]*wv.z + s1[k4*4+3]*wv.w;
        }
    }
    s0[t] = fmaxf(acc, 0.f);
    __syncthreads();

    red[t] = s0[t] * oW[t];
    __syncthreads();
    for (int off = 128; off > 0; off >>= 1) {
        if (t < off) red[t] += red[t + off];
        __syncthreads();
    }
    if (t == 0) out[g] = red[0] + ob[0];
}

extern "C" void kernel_launch(void* const* d_in, const int* in_sizes, int n_in,
                              void* d_out, int out_size, void* d_ws, size_t ws_size,
                              hipStream_t stream) {
    const float* x     = (const float*)d_in[0];
    const int*   ei    = (const int*)d_in[1];
    const int*   batch = (const int*)d_in[2];
    const float* mol   = (const float*)d_in[3];
    const float* gcnW  = (const float*)d_in[4];
    const float* gcnb  = (const float*)d_in[5];
    const float* gcnoW = (const float*)d_in[6];
    const float* gcnob = (const float*)d_in[7];
    const float* mlpW  = (const float*)d_in[8];
    const float* mlpb  = (const float*)d_in[9];
    const float* mloW  = (const float*)d_in[10];
    const float* mlob  = (const float*)d_in[11];
    const float* pW1   = (const float*)d_in[12];
    const float* pb1   = (const float*)d_in[13];
    const float* pW2   = (const float*)d_in[14];
    const float* pb2   = (const float*)d_in[15];
    const float* oW    = (const float*)d_in[16];
    const float* ob    = (const float*)d_in[17];

    const int N = in_sizes[0] / 128;
    const int E = in_sizes[1] / 2;
    const int G = in_sizes[3] / 256;
    const int* row = ei;
    const int* col = ei + E;

    char* p = (char*)d_ws;
    auto alloc = [&](size_t bytes) {
        char* q = p;
        p += (bytes + 255) & ~(size_t)255;
        return (void*)q;
    };
    int*   deg     = (int*)alloc((size_t)N * 4);
    int*   rowptr  = (int*)alloc((size_t)(N + 1) * 4);
    int*   cursor  = (int*)alloc((size_t)N * 4);
    int*   csr_src = (int*)alloc((size_t)(E + 16) * 4);
    float* csr_w   = (float*)alloc((size_t)(E + 16) * 4);
    float* dinv    = (float*)alloc((size_t)N * 4);
    float* buf0    = (float*)alloc((size_t)N * 128 * 4);
    float* buf1    = (float*)alloc((size_t)N * 128 * 4);
    float* WT      = (float*)alloc((size_t)3 * 128 * 128 * 4);
    float* pool    = (float*)alloc((size_t)G * 128 * 4);
    float* cnt     = (float*)alloc((size_t)G * 4);
    int*   bsum    = (int*)alloc(256 * 4);

    const int NB = (N + 255) / 256;   // 196 <= 256, required by k_scan2

    k_zero<<<(N + 255) / 256, 256, 0, stream>>>(deg, pool, cnt, csr_src + E, N, G);
    k_degree<<<(E + 255) / 256, 256, 0, stream>>>(col, deg, E);
    k_scan1<<<NB, 256, 0, stream>>>(deg, bsum, N);
    k_scan2<<<1, 256, 0, stream>>>(bsum, NB);
    k_scan3<<<NB, 256, 0, stream>>>(deg, bsum, rowptr, cursor, dinv, N, E);
    k_scatter<<<(E + 255) / 256, 256, 0, stream>>>(row, col, dinv, cursor,
                                                   csr_src, csr_w, E);
    k_transpose_w<<<192, 256, 0, stream>>>(gcnW, WT);

    const int mmblocks = (N + 63) / 64;
    const int aggblocks = (N + 3) / 4;
    const float* src = x;
    for (int l = 0; l < 3; ++l) {
        k_agg<<<aggblocks, 256, 0, stream>>>(src, buf0, dinv, rowptr,
                                             csr_src, csr_w, N);
        k_matmul<<<mmblocks, 256, 0, stream>>>(buf0, WT + (size_t)l * 16384,
                                               gcnb + (size_t)l * 128, buf1, N);
        src = buf1;
    }
    k_pool<<<NB, 256, 0, stream>>>(buf1, batch, pool, cnt, N);
    k_head<<<G, 256, 0, stream>>>(pool, cnt, gcnoW, gcnob, mol, mlpW, mlpb,
                                  mloW, mlob, pW1, pb1, pW2, pb2, oW, ob,
                                  (float*)d_out);
}

// Round 4
// 394.109 us; speedup vs baseline: 1.4469x; 1.4469x over previous
//
#include <hip/hip_runtime.h>

// ---------------------------------------------------------------------------
// GCN model, re-associated: per layer h = relu((A_hat @ h_prev) @ W^T + b);
// pool BEFORE gcn_out linear. Node features stored BF16 (fp32 accumulate):
// halves the random-gather traffic (the measured ceiling) and enables MFMA
// bf16 matmuls. CSR entries packed (src,dinv) into 8B.
// ---------------------------------------------------------------------------

typedef __attribute__((ext_vector_type(8))) short short8;   // MFMA A/B frag
typedef __attribute__((ext_vector_type(4))) float f32x4;    // MFMA C/D frag

__device__ __forceinline__ unsigned short f2bf(float f) {
    union { float f; unsigned u; } c; c.f = f;
    unsigned u = c.u;
    unsigned r = u + 0x7FFFu + ((u >> 16) & 1u);   // RNE
    return (unsigned short)(r >> 16);
}
__device__ __forceinline__ float bflo(unsigned w) {
    union { unsigned u; float f; } c; c.u = w << 16; return c.f;
}
__device__ __forceinline__ float bfhi(unsigned w) {
    union { unsigned u; float f; } c; c.u = w & 0xFFFF0000u; return c.f;
}

__global__ void k_zero(int* deg, float* pool, float* cnt, int* csr_pad,
                       int N, int G) {
    int i = blockIdx.x * blockDim.x + threadIdx.x;
    if (i < N) deg[i] = 0;
    if (i < G * 128) pool[i] = 0.f;
    if (i < G) cnt[i] = 0.f;
    if (i < 32) csr_pad[i] = 0;          // 16 packed 8B pad entries
}

// x fp32 -> bf16 (8 elems/thread)
__global__ void k_castx(const float* __restrict__ x, unsigned short* __restrict__ xb,
                        int total8) {
    int i = blockIdx.x * blockDim.x + threadIdx.x;
    if (i >= total8) return;
    const float4* s = (const float4*)(x + (size_t)i * 8);
    float4 a = s[0], b = s[1];
    uint4 o;
    o.x = ((unsigned)f2bf(a.y) << 16) | f2bf(a.x);
    o.y = ((unsigned)f2bf(a.w) << 16) | f2bf(a.z);
    o.z = ((unsigned)f2bf(b.y) << 16) | f2bf(b.x);
    o.w = ((unsigned)f2bf(b.w) << 16) | f2bf(b.z);
    *(uint4*)(xb + (size_t)i * 8) = o;
}

// gcn_W (3,128,128) fp32 -> bf16, pre-swizzled 16B chunks:
// dst chunk index = l*2048 + o*16 + (c ^ (o&15)), chunk c = k/8.
__global__ void k_wcast(const float* __restrict__ gcnW, uint4* __restrict__ Wb) {
    int cid = blockIdx.x * 256 + threadIdx.x;   // 6144 chunks
    if (cid >= 3 * 2048) return;
    int l = cid >> 11, rem = cid & 2047;
    int o = rem >> 4, c = rem & 15;
    const float4* s = (const float4*)(gcnW + (size_t)l * 16384 + o * 128 + c * 8);
    float4 a = s[0], b = s[1];
    uint4 v;
    v.x = ((unsigned)f2bf(a.y) << 16) | f2bf(a.x);
    v.y = ((unsigned)f2bf(a.w) << 16) | f2bf(a.z);
    v.z = ((unsigned)f2bf(b.y) << 16) | f2bf(b.x);
    v.w = ((unsigned)f2bf(b.w) << 16) | f2bf(b.z);
    Wb[(l << 11) | (o << 4) | (c ^ (o & 15))] = v;
}

__global__ void k_degree(const int* __restrict__ col, int* __restrict__ deg, int E) {
    int e = blockIdx.x * blockDim.x + threadIdx.x;
    if (e < E) atomicAdd(&deg[col[e]], 1);
}

// ---- 3-phase multi-block exclusive scan of deg -> rowptr/cursor (+dinv) ----
__global__ __launch_bounds__(256) void k_scan1(const int* __restrict__ deg,
                                               int* __restrict__ bsum, int N) {
    int t = threadIdx.x;
    int i = blockIdx.x * 256 + t;
    int v = (i < N) ? deg[i] : 0;
    #pragma unroll
    for (int off = 32; off > 0; off >>= 1) v += __shfl_xor(v, off, 64);
    __shared__ int ws[4];
    if ((t & 63) == 0) ws[t >> 6] = v;
    __syncthreads();
    if (t == 0) bsum[blockIdx.x] = ws[0] + ws[1] + ws[2] + ws[3];
}

__global__ __launch_bounds__(256) void k_scan2(int* __restrict__ bsum, int NB) {
    int t = threadIdx.x, lane = t & 63, wv = t >> 6;
    int v = (t < NB) ? bsum[t] : 0;
    int x = v;
    #pragma unroll
    for (int off = 1; off < 64; off <<= 1) {
        int u = __shfl_up(x, off, 64);
        if (lane >= off) x += u;
    }
    __shared__ int ws[4];
    if (lane == 63) ws[wv] = x;
    __syncthreads();
    int woff = 0;
    for (int w = 0; w < wv; ++w) woff += ws[w];
    if (t < NB) bsum[t] = woff + x - v;
}

__global__ __launch_bounds__(256) void k_scan3(const int* __restrict__ deg,
                                               const int* __restrict__ bsum,
                                               int* __restrict__ rowptr,
                                               int* __restrict__ cursor,
                                               float* __restrict__ dinv,
                                               int N, int E) {
    int t = threadIdx.x, lane = t & 63, wv = t >> 6;
    int i = blockIdx.x * 256 + t;
    int v = (i < N) ? deg[i] : 0;
    int x = v;
    #pragma unroll
    for (int off = 1; off < 64; off <<= 1) {
        int u = __shfl_up(x, off, 64);
        if (lane >= off) x += u;
    }
    __shared__ int ws[4];
    if (lane == 63) ws[wv] = x;
    __syncthreads();
    int woff = 0;
    for (int w = 0; w < wv; ++w) woff += ws[w];
    int excl = bsum[blockIdx.x] + woff + (x - v);
    if (i < N) {
        rowptr[i] = excl;
        cursor[i] = excl;
        dinv[i] = rsqrtf((float)v + 1.0f);
    }
    if (i == 0) rowptr[N] = E;
}

// CSR entry packed: low word = dinv[src] bits, high word = src.
__global__ void k_scatter(const int* __restrict__ row, const int* __restrict__ col,
                          const float* __restrict__ dinv,
                          int* __restrict__ cursor,
                          unsigned long long* __restrict__ csr, int E) {
    int e = blockIdx.x * blockDim.x + threadIdx.x;
    if (e < E) {
        int pos = atomicAdd(&cursor[col[e]], 1);
        int r = row[e];
        union { float f; unsigned u; } w; w.f = dinv[r];
        csr[pos] = ((unsigned long long)(unsigned)r << 32) | w.u;
    }
}

// y[n] = dinv[n] * sum csr_w*h[src] + dinv[n]^2 * h[n]   (h, y bf16)
// One wave per node, 4/block. 16 fg (16B=8 bf16 each) x 4 neighbor slots.
__global__ __launch_bounds__(256) void k_agg(const unsigned short* __restrict__ h,
                                             unsigned short* __restrict__ y,
                                             const float* __restrict__ dinv,
                                             const int* __restrict__ rowptr,
                                             const uint2* __restrict__ csr,
                                             int N) {
    const int lane = threadIdx.x & 63;
    const int n = blockIdx.x * 4 + (threadIdx.x >> 6);
    if (n >= N) return;
    const int fg = lane & 15;
    const int slot = lane >> 4;
    const int s = rowptr[n], e = rowptr[n + 1];

    float acc[8] = {0.f, 0.f, 0.f, 0.f, 0.f, 0.f, 0.f, 0.f};
    for (int base = s; base < e; base += 16) {
        int li = base + fg;
        uint2 pk = csr[li];                              // padded: in-bounds
        float w_l = (li < e) ? bflo(pk.x >> 16) : 0.f;   // reinterp fp32 bits
        w_l = (li < e) ? __uint_as_float(pk.x) : 0.f;
        int src_l = (int)pk.y;
        #pragma unroll
        for (int i = 0; i < 4; ++i) {
            int j = i * 4 + slot;
            int src = __shfl(src_l, j, 16);
            float w = __shfl(w_l, j, 16);
            uint4 v = *(const uint4*)(h + (size_t)src * 128 + fg * 8);
            acc[0] += w * bflo(v.x); acc[1] += w * bfhi(v.x);
            acc[2] += w * bflo(v.y); acc[3] += w * bfhi(v.y);
            acc[4] += w * bflo(v.z); acc[5] += w * bfhi(v.z);
            acc[6] += w * bflo(v.w); acc[7] += w * bfhi(v.w);
        }
    }
    #pragma unroll
    for (int r = 0; r < 8; ++r) {
        acc[r] += __shfl_xor(acc[r], 16, 64);
        acc[r] += __shfl_xor(acc[r], 32, 64);
    }
    if (slot == 0) {
        float dn = dinv[n], dn2 = dn * dn;
        uint4 hv = *(const uint4*)(h + (size_t)n * 128 + fg * 8);
        float sv[8] = {bflo(hv.x), bfhi(hv.x), bflo(hv.y), bfhi(hv.y),
                       bflo(hv.z), bfhi(hv.z), bflo(hv.w), bfhi(hv.w)};
        unsigned short ob[8];
        #pragma unroll
        for (int r = 0; r < 8; ++r) ob[r] = f2bf(acc[r] * dn + dn2 * sv[r]);
        uint4 o;
        o.x = ((unsigned)ob[1] << 16) | ob[0];
        o.y = ((unsigned)ob[3] << 16) | ob[2];
        o.z = ((unsigned)ob[5] << 16) | ob[4];
        o.w = ((unsigned)ob[7] << 16) | ob[6];
        *(uint4*)(y + (size_t)n * 128 + fg * 8) = o;
    }
}

// C[N,128] = relu(A @ W^T + b) in bf16 via MFMA 16x16x32_bf16.
// A bf16 row-major (frags straight from global); W pre-swizzled bf16 in LDS.
// Block: 256 thr = 4 waves x 16 rows; per wave 8 col-tiles x 4 K-steps.
__global__ __launch_bounds__(256) void k_mm(const unsigned short* __restrict__ A,
                                            const uint4* __restrict__ Wb,
                                            const float* __restrict__ bias,
                                            unsigned short* __restrict__ C, int N) {
    __shared__ uint4 Wsh[2048];   // 32 KB, swizzled [o][c^(o&15)]
    const int tid = threadIdx.x;
    #pragma unroll
    for (int it = 0; it < 8; ++it)
        Wsh[tid + it * 256] = Wb[tid + it * 256];

    const int lane = tid & 63;
    const int wv = tid >> 6;
    const int l15 = lane & 15, quad = lane >> 4;
    const int arow_i = blockIdx.x * 64 + wv * 16 + l15;
    const unsigned short* arow = A + (size_t)min(arow_i, N - 1) * 128;

    f32x4 acc[8];
    #pragma unroll
    for (int ct = 0; ct < 8; ++ct) acc[ct] = (f32x4){0.f, 0.f, 0.f, 0.f};

    __syncthreads();
    #pragma unroll
    for (int kiter = 0; kiter < 4; ++kiter) {
        short8 af = *(const short8*)(arow + kiter * 32 + quad * 8);
        const int cswz = (kiter * 4 + quad) ^ l15;   // o&15 == l15 for all ct
        #pragma unroll
        for (int ct = 0; ct < 8; ++ct) {
            short8 bf = *(const short8*)(&Wsh[((ct * 16 + l15) << 4) | cswz]);
            acc[ct] = __builtin_amdgcn_mfma_f32_16x16x32_bf16(af, bf, acc[ct], 0, 0, 0);
        }
    }

    const int rbase = blockIdx.x * 64 + wv * 16 + quad * 4;
    #pragma unroll
    for (int ct = 0; ct < 8; ++ct) {
        int colc = ct * 16 + l15;
        float bcol = bias[colc];
        #pragma unroll
        for (int r = 0; r < 4; ++r) {
            int rr = rbase + r;
            if (rr < N) {
                float v = fmaxf(acc[ct][r] + bcol, 0.f);
                C[(size_t)rr * 128 + colc] = f2bf(v);
            }
        }
    }
}

// Mean-pool accumulate (batch sorted), bf16 input, fp32 atomics out.
// 16 subgroups of 16 lanes; each subgroup 32 nodes; lane = 16B chunk.
__global__ __launch_bounds__(256) void k_pool(const unsigned short* __restrict__ h,
                                              const int* __restrict__ batch,
                                              float* __restrict__ pool,
                                              float* __restrict__ cnt, int N) {
    int t = threadIdx.x;
    int fg = t & 15, sg = t >> 4;
    int n0 = blockIdx.x * 512 + sg * 32;
    if (n0 >= N) return;
    int n1 = min(n0 + 32, N);
    int gprev = batch[n0];
    float racc[8] = {0.f, 0.f, 0.f, 0.f, 0.f, 0.f, 0.f, 0.f};
    float rcnt = 0.f;
    for (int n = n0; n < n1; ++n) {
        int g = batch[n];
        if (g != gprev) {
            float* dst = pool + (size_t)gprev * 128 + fg * 8;
            #pragma unroll
            for (int r = 0; r < 8; ++r) atomicAdd(dst + r, racc[r]);
            if (fg == 0) atomicAdd(&cnt[gprev], rcnt);
            #pragma unroll
            for (int r = 0; r < 8; ++r) racc[r] = 0.f;
            rcnt = 0.f; gprev = g;
        }
        uint4 v = *(const uint4*)(h + (size_t)n * 128 + fg * 8);
        racc[0] += bflo(v.x); racc[1] += bfhi(v.x);
        racc[2] += bflo(v.y); racc[3] += bfhi(v.y);
        racc[4] += bflo(v.z); racc[5] += bfhi(v.z);
        racc[6] += bflo(v.w); racc[7] += bfhi(v.w);
        rcnt += 1.f;
    }
    float* dst = pool + (size_t)gprev * 128 + fg * 8;
    #pragma unroll
    for (int r = 0; r < 8; ++r) atomicAdd(dst + r, racc[r]);
    if (fg == 0) atomicAdd(&cnt[gprev], rcnt);
}

// Fused head (fp32). gcn branch: mean -> gcn_out linear (moved after pooling).
__global__ __launch_bounds__(256) void k_head(
    const float* __restrict__ pool, const float* __restrict__ cnt,
    const float* __restrict__ gcnoW, const float* __restrict__ gcnob,
    const float* __restrict__ mol,
    const float* __restrict__ mlpW, const float* __restrict__ mlpb,
    const float* __restrict__ mloW, const float* __restrict__ mlob,
    const float* __restrict__ pW1, const float* __restrict__ pb1,
    const float* __restrict__ pW2, const float* __restrict__ pb2,
    const float* __restrict__ oW, const float* __restrict__ ob,
    float* __restrict__ out) {
    int g = blockIdx.x, t = threadIdx.x;
    __shared__ float s0[256], s1[256], s2[192], mean[128], red[256];

    s0[t] = mol[(size_t)g * 256 + t];
    if (t < 128) {
        float c = cnt[g];
        mean[t] = pool[(size_t)g * 128 + t] / fmaxf(c, 1.f);
    }
    __syncthreads();

    float acc = mlpb[t];
    {
        const float4* w = (const float4*)(mlpW + (size_t)t * 256);
        #pragma unroll 4
        for (int k4 = 0; k4 < 64; ++k4) {
            float4 wv = w[k4];
            acc += s0[k4*4+0]*wv.x + s0[k4*4+1]*wv.y + s0[k4*4+2]*wv.z + s0[k4*4+3]*wv.w;
        }
    }
    s1[t] = fmaxf(acc, 0.f);
    __syncthreads();

    acc = mlpb[256 + t];
    {
        const float4* w = (const float4*)(mlpW + 65536 + (size_t)t * 256);
        #pragma unroll 4
        for (int k4 = 0; k4 < 64; ++k4) {
            float4 wv = w[k4];
            acc += s1[k4*4+0]*wv.x + s1[k4*4+1]*wv.y + s1[k4*4+2]*wv.z + s1[k4*4+3]*wv.w;
        }
    }
    s0[t] = fmaxf(acc, 0.f);
    __syncthreads();

    if (t < 64) {
        float a2 = mlob[t];
        const float4* w = (const float4*)(mloW + (size_t)t * 256);
        #pragma unroll 4
        for (int k4 = 0; k4 < 64; ++k4) {
            float4 wv = w[k4];
            a2 += s0[k4*4+0]*wv.x + s0[k4*4+1]*wv.y + s0[k4*4+2]*wv.z + s0[k4*4+3]*wv.w;
        }
        s2[128 + t] = fmaxf(a2, 0.f);
    } else if (t < 192) {
        int o = t - 64;
        float a2 = gcnob[o];
        const float4* w = (const float4*)(gcnoW + (size_t)o * 128);
        #pragma unroll 4
        for (int k4 = 0; k4 < 32; ++k4) {
            float4 wv = w[k4];
            a2 += mean[k4*4+0]*wv.x + mean[k4*4+1]*wv.y + mean[k4*4+2]*wv.z + mean[k4*4+3]*wv.w;
        }
        s2[o] = a2;   // no relu on gcn_out
    }
    __syncthreads();

    acc = pb1[t];
    {
        const float4* w = (const float4*)(pW1 + (size_t)t * 192);
        #pragma unroll 4
        for (int k4 = 0; k4 < 48; ++k4) {
            float4 wv = w[k4];
            acc += s2[k4*4+0]*wv.x + s2[k4*4+1]*wv.y + s2[k4*4+2]*wv.z + s2[k4*4+3]*wv.w;
        }
    }
    s1[t] = fmaxf(acc, 0.f);
    __syncthreads();

    acc = pb2[t];
    {
        const float4* w = (const float4*)(pW2 + (size_t)t * 256);
        #pragma unroll 4
        for (int k4 = 0; k4 < 64; ++k4) {
            float4 wv = w[k4];
            acc += s1[k4*4+0]*wv.x + s1[k4*4+1]*wv.y + s1[k4*4+2]*wv.z + s1[k4*4+3]*wv.w;
        }
    }
    s0[t] = fmaxf(acc, 0.f);
    __syncthreads();

    red[t] = s0[t] * oW[t];
    __syncthreads();
    for (int off = 128; off > 0; off >>= 1) {
        if (t < off) red[t] += red[t + off];
        __syncthreads();
    }
    if (t == 0) out[g] = red[0] + ob[0];
}

extern "C" void kernel_launch(void* const* d_in, const int* in_sizes, int n_in,
                              void* d_out, int out_size, void* d_ws, size_t ws_size,
                              hipStream_t stream) {
    const float* x     = (const float*)d_in[0];
    const int*   ei    = (const int*)d_in[1];
    const int*   batch = (const int*)d_in[2];
    const float* mol   = (const float*)d_in[3];
    const float* gcnW  = (const float*)d_in[4];
    const float* gcnb  = (const float*)d_in[5];
    const float* gcnoW = (const float*)d_in[6];
    const float* gcnob = (const float*)d_in[7];
    const float* mlpW  = (const float*)d_in[8];
    const float* mlpb  = (const float*)d_in[9];
    const float* mloW  = (const float*)d_in[10];
    const float* mlob  = (const float*)d_in[11];
    const float* pW1   = (const float*)d_in[12];
    const float* pb1   = (const float*)d_in[13];
    const float* pW2   = (const float*)d_in[14];
    const float* pb2   = (const float*)d_in[15];
    const float* oW    = (const float*)d_in[16];
    const float* ob    = (const float*)d_in[17];

    const int N = in_sizes[0] / 128;
    const int E = in_sizes[1] / 2;
    const int G = in_sizes[3] / 256;
    const int* row = ei;
    const int* col = ei + E;

    char* p = (char*)d_ws;
    auto alloc = [&](size_t bytes) {
        char* q = p;
        p += (bytes + 255) & ~(size_t)255;
        return (void*)q;
    };
    int*    deg    = (int*)alloc((size_t)N * 4);
    int*    rowptr = (int*)alloc((size_t)(N + 1) * 4);
    int*    cursor = (int*)alloc((size_t)N * 4);
    unsigned long long* csr = (unsigned long long*)alloc((size_t)(E + 16) * 8);
    float*  dinv   = (float*)alloc((size_t)N * 4);
    unsigned short* xb   = (unsigned short*)alloc((size_t)N * 128 * 2);
    unsigned short* bufA = (unsigned short*)alloc((size_t)N * 128 * 2);
    unsigned short* bufB = (unsigned short*)alloc((size_t)N * 128 * 2);
    uint4*  Wb     = (uint4*)alloc((size_t)3 * 2048 * 16);
    float*  pool   = (float*)alloc((size_t)G * 128 * 4);
    float*  cnt    = (float*)alloc((size_t)G * 4);
    int*    bsum   = (int*)alloc(256 * 4);

    const int NB = (N + 255) / 256;   // 196 <= 256 (k_scan2 requirement)

    k_zero<<<NB, 256, 0, stream>>>(deg, pool, cnt, (int*)(csr + E), N, G);
    k_castx<<<(N * 16 + 255) / 256, 256, 0, stream>>>(x, xb, N * 16);
    k_wcast<<<24, 256, 0, stream>>>(gcnW, Wb);
    k_degree<<<(E + 255) / 256, 256, 0, stream>>>(col, deg, E);
    k_scan1<<<NB, 256, 0, stream>>>(deg, bsum, N);
    k_scan2<<<1, 256, 0, stream>>>(bsum, NB);
    k_scan3<<<NB, 256, 0, stream>>>(deg, bsum, rowptr, cursor, dinv, N, E);
    k_scatter<<<(E + 255) / 256, 256, 0, stream>>>(row, col, dinv, cursor, csr, E);

    const int mmblocks = (N + 63) / 64;
    const int aggblocks = (N + 3) / 4;
    const unsigned short* src = xb;
    for (int l = 0; l < 3; ++l) {
        k_agg<<<aggblocks, 256, 0, stream>>>(src, bufA, dinv, rowptr,
                                             (const uint2*)csr, N);
        k_mm<<<mmblocks, 256, 0, stream>>>(bufA, Wb + (size_t)l * 2048,
                                           gcnb + (size_t)l * 128, bufB, N);
        src = bufB;
    }
    k_pool<<<(N + 511) / 512, 256, 0, stream>>>(bufB, batch, pool, cnt, N);
    k_head<<<G, 256, 0, stream>>>(pool, cnt, gcnoW, gcnob, mol, mlpW, mlpb,
                                  mloW, mlob, pW1, pb1, pW2, pb2, oW, ob,
                                  (float*)d_out);
}